// Round 13
// baseline (408.926 us; speedup 1.0000x reference)
//
#include <hip/hip_runtime.h>
#include <math.h>

#define NN 16384
#define EE 262144
#define FF 32
#define HH 128
#define BB 16
#define DI 256
#define DS 16
#define DC 4
#define DTR 8
#define OUTW 1552
#define NCH 256
#define CHLEN 64    // NCH*CHLEN == NN

// ---------------------------------------------------------------- utilities
__device__ __forceinline__ float siluf(float v) { return v / (1.f + __expf(-v)); }
__device__ __forceinline__ float softplusf(float v) {
    return fmaxf(v, 0.f) + __logf(1.f + __expf(-fabsf(v)));
}

// ---------------------------------------------------------------- zero scratch (replaces 3 memsets)
__global__ void zero_kernel(int* __restrict__ cnt, float* __restrict__ ge,
                            int* __restrict__ counts) {
    int idx = blockIdx.x * blockDim.x + threadIdx.x;
    if (idx < NN) cnt[idx] = 0;
    if (idx < BB * HH) ge[idx] = 0.f;
    if (idx < BB) counts[idx] = 0;
}

// ---------------------------------------------------------------- CSR build
__global__ void deg_kernel(const int* __restrict__ dst, int* __restrict__ cnt) {
    int e = blockIdx.x * blockDim.x + threadIdx.x;
    if (e < EE) atomicAdd(&cnt[dst[e]], 1);
}

__global__ __launch_bounds__(1024) void prefix_kernel(const int* __restrict__ cnt,
                                                      int* __restrict__ rowptr,
                                                      int* __restrict__ cursor,
                                                      float* __restrict__ dinv) {
    __shared__ int part[1024];
    int tid = threadIdx.x;
    int4 c4[4];
#pragma unroll
    for (int j = 0; j < 4; j++) c4[j] = ((const int4*)cnt)[tid * 4 + j];
    int v[16] = {c4[0].x, c4[0].y, c4[0].z, c4[0].w, c4[1].x, c4[1].y, c4[1].z, c4[1].w,
                 c4[2].x, c4[2].y, c4[2].z, c4[2].w, c4[3].x, c4[3].y, c4[3].z, c4[3].w};
    int s = 0;
#pragma unroll
    for (int j = 0; j < 16; j++) s += v[j];
    part[tid] = s;
    __syncthreads();
    for (int off = 1; off < 1024; off <<= 1) {
        int t = (tid >= off) ? part[tid - off] : 0;
        __syncthreads();
        part[tid] += t;
        __syncthreads();
    }
    int running = part[tid] - s;
    int rp[16];
    float dv[16];
#pragma unroll
    for (int j = 0; j < 16; j++) {
        rp[j] = running;
        running += v[j];
        dv[j] = rsqrtf((float)(v[j] + 1));  // +1 self loop
    }
#pragma unroll
    for (int j = 0; j < 4; j++) {
        int4 r4; r4.x = rp[j*4]; r4.y = rp[j*4+1]; r4.z = rp[j*4+2]; r4.w = rp[j*4+3];
        ((int4*)rowptr)[tid * 4 + j] = r4;
        ((int4*)cursor)[tid * 4 + j] = r4;
        float4 d4; d4.x = dv[j*4]; d4.y = dv[j*4+1]; d4.z = dv[j*4+2]; d4.w = dv[j*4+3];
        ((float4*)dinv)[tid * 4 + j] = d4;
    }
    if (tid == 1023) rowptr[NN] = part[1023];
}

__global__ void scatter_kernel(const int* __restrict__ src, const int* __restrict__ dst,
                               int* __restrict__ cursor, int* __restrict__ col) {
    int e = blockIdx.x * blockDim.x + threadIdx.x;
    if (e < EE) {
        int d = dst[e];
        int pos = atomicAdd(&cursor[d], 1);
        col[pos] = src[e];
    }
}

// ---------------------------------------------------------------- GEMM (fp32, 64x64 tile)
__global__ __launch_bounds__(256) void gemm_k(const float* __restrict__ A,
                                              const float* __restrict__ B,
                                              const float* __restrict__ bias,
                                              float* __restrict__ C,
                                              int M, int Nn, int K, int act) {
    __shared__ float As[16][68];
    __shared__ float Bs[16][68];
    int tid = threadIdx.x;
    int m0 = blockIdx.y * 64;
    int n0 = blockIdx.x * 64;
    int ty = tid >> 4, tx = tid & 15;
    float acc[4][4] = {{0.f}};
    for (int k0 = 0; k0 < K; k0 += 16) {
#pragma unroll
        for (int l = 0; l < 4; l++) {
            int idx = tid + l * 256;
            int i = idx >> 4, j = idx & 15;
            As[j][i] = A[(size_t)(m0 + i) * K + k0 + j];
        }
#pragma unroll
        for (int l = 0; l < 4; l++) {
            int idx = tid + l * 256;
            int i = idx >> 6, j = idx & 63;
            int n = n0 + j;
            Bs[i][j] = (n < Nn) ? B[(size_t)(k0 + i) * Nn + n] : 0.f;
        }
        __syncthreads();
#pragma unroll
        for (int kk = 0; kk < 16; kk++) {
            float4 a4 = *(const float4*)&As[kk][ty * 4];
            float4 b4 = *(const float4*)&Bs[kk][tx * 4];
            float av[4] = {a4.x, a4.y, a4.z, a4.w};
            float bv[4] = {b4.x, b4.y, b4.z, b4.w};
#pragma unroll
            for (int r = 0; r < 4; r++)
#pragma unroll
                for (int c = 0; c < 4; c++) acc[r][c] = fmaf(av[r], bv[c], acc[r][c]);
        }
        __syncthreads();
    }
    int nb = n0 + tx * 4;
    if (nb < Nn) {
        float4 bi4 = {0.f, 0.f, 0.f, 0.f};
        if (bias) bi4 = *(const float4*)&bias[nb];
#pragma unroll
        for (int r = 0; r < 4; r++) {
            int m = m0 + ty * 4 + r;
            float4 v;
            v.x = acc[r][0] + bi4.x; v.y = acc[r][1] + bi4.y;
            v.z = acc[r][2] + bi4.z; v.w = acc[r][3] + bi4.w;
            if (act == 1) {
                v.x = fmaxf(v.x, 0.f); v.y = fmaxf(v.y, 0.f);
                v.z = fmaxf(v.z, 0.f); v.w = fmaxf(v.w, 0.f);
            }
            *(float4*)&C[(size_t)m * Nn + nb] = v;
        }
    }
}

// ---------------------------------------------------------------- big-tile GEMM, 512 threads
__global__ __launch_bounds__(512, 4) void gemm_big512(const float* __restrict__ A,
                                                      const float* __restrict__ B,
                                                      float* __restrict__ C,
                                                      int M, int Nn, int K) {
    __shared__ float As[16][132];
    __shared__ float Bs[16][132];
    int tid = threadIdx.x;
    int m0 = blockIdx.y * 128;
    int n0 = blockIdx.x * 128;
    int ty = tid >> 4;
    int tx = tid & 15;
    float acc[4][8] = {{0.f}};
    for (int k0 = 0; k0 < K; k0 += 16) {
        {
            int m = tid >> 2;
            int kc = (tid & 3) * 4;
            float4 a = *(const float4*)&A[(size_t)(m0 + m) * K + k0 + kc];
            As[kc + 0][m] = a.x; As[kc + 1][m] = a.y;
            As[kc + 2][m] = a.z; As[kc + 3][m] = a.w;
        }
        {
            int krow = tid >> 5;
            int c4 = (tid & 31) * 4;
            *(float4*)&Bs[krow][c4] = *(const float4*)&B[(size_t)(k0 + krow) * Nn + n0 + c4];
        }
        __syncthreads();
#pragma unroll
        for (int kk = 0; kk < 16; kk++) {
            float4 a4 = *(const float4*)&As[kk][ty * 4];
            float4 b0 = *(const float4*)&Bs[kk][tx * 4];
            float4 b1 = *(const float4*)&Bs[kk][64 + tx * 4];
            float av[4] = {a4.x, a4.y, a4.z, a4.w};
            float bv[8] = {b0.x, b0.y, b0.z, b0.w, b1.x, b1.y, b1.z, b1.w};
#pragma unroll
            for (int r = 0; r < 4; r++)
#pragma unroll
                for (int c = 0; c < 8; c++) acc[r][c] = fmaf(av[r], bv[c], acc[r][c]);
        }
        __syncthreads();
    }
#pragma unroll
    for (int r = 0; r < 4; r++) {
        int m = m0 + ty * 4 + r;
        float4 v0, v1;
        v0.x = acc[r][0]; v0.y = acc[r][1]; v0.z = acc[r][2]; v0.w = acc[r][3];
        v1.x = acc[r][4]; v1.y = acc[r][5]; v1.z = acc[r][6]; v1.w = acc[r][7];
        *(float4*)&C[(size_t)m * Nn + n0 + tx * 4] = v0;
        *(float4*)&C[(size_t)m * Nn + n0 + 64 + tx * 4] = v1;
    }
}

// ---------------------------------------------------------------- xproj GEMM (A^T) + transposed output
__global__ __launch_bounds__(256) void gemm_at_dblt(const float* __restrict__ AT,
                                                    const float* __restrict__ B,
                                                    float* __restrict__ dblt) {
    __shared__ float As[16][68];
    __shared__ float Bs[16][68];
    __shared__ float Ct[64][41];
    int tid = threadIdx.x;
    int m0 = blockIdx.x * 64;
    int ty = tid >> 4, tx = tid & 15;
    float acc[4][4] = {{0.f}};
    for (int k0 = 0; k0 < DI; k0 += 16) {
#pragma unroll
        for (int l = 0; l < 4; l++) {
            int idx = tid + l * 256;
            int kk = idx >> 6, i = idx & 63;
            As[kk][i] = AT[(size_t)(k0 + kk) * NN + m0 + i];
        }
#pragma unroll
        for (int l = 0; l < 4; l++) {
            int idx = tid + l * 256;
            int i = idx >> 6, j = idx & 63;
            Bs[i][j] = (j < 40) ? B[(size_t)(k0 + i) * 40 + j] : 0.f;
        }
        __syncthreads();
#pragma unroll
        for (int kk = 0; kk < 16; kk++) {
            float4 a4 = *(const float4*)&As[kk][ty * 4];
            float4 b4 = *(const float4*)&Bs[kk][tx * 4];
            float av[4] = {a4.x, a4.y, a4.z, a4.w};
            float bv[4] = {b4.x, b4.y, b4.z, b4.w};
#pragma unroll
            for (int r = 0; r < 4; r++)
#pragma unroll
                for (int c = 0; c < 4; c++) acc[r][c] = fmaf(av[r], bv[c], acc[r][c]);
        }
        __syncthreads();
    }
    if (tx * 4 < 40) {
#pragma unroll
        for (int r = 0; r < 4; r++) {
            int m = ty * 4 + r;
            Ct[m][tx * 4 + 0] = acc[r][0];
            Ct[m][tx * 4 + 1] = acc[r][1];
            Ct[m][tx * 4 + 2] = acc[r][2];
            Ct[m][tx * 4 + 3] = acc[r][3];
        }
    }
    __syncthreads();
#pragma unroll
    for (int l = 0; l < 10; l++) {
        int idx = tid + l * 256;
        int n = idx >> 6, m = idx & 63;
        dblt[(size_t)n * NN + m0 + m] = Ct[m][n];
    }
}

// ---------------------------------------------------------------- fused W_out GEMM + add + LN + POOL
// 32m x 128n tile; LN per row, then pooled directly into GE (batch sorted ->
// fast path: whole block one batch, LDS reduction + 128 global atomics).
__global__ __launch_bounds__(256) void gemm_at_ln_pool(const float* __restrict__ AT,
                                                       const float* __restrict__ B,
                                                       const float* __restrict__ hg,
                                                       const float* __restrict__ gamma,
                                                       const float* __restrict__ beta,
                                                       const int* __restrict__ batch,
                                                       float* __restrict__ ge,
                                                       int* __restrict__ counts) {
    __shared__ float As[16][36];
    __shared__ float Bs[16][132];
    __shared__ float gsum[128];
    int tid = threadIdx.x;
    int m0 = blockIdx.x * 32;
    int ty = tid >> 4, tx = tid & 15;
    float acc[2][8] = {{0.f}};
    for (int k0 = 0; k0 < 256; k0 += 16) {
        {
            int idx = tid * 2;
            int kk = idx >> 5, i = idx & 31;
            As[kk][i] = AT[(size_t)(k0 + kk) * NN + m0 + i];
            As[kk][i + 1] = AT[(size_t)(k0 + kk) * NN + m0 + i + 1];
        }
        {
            int krow = tid >> 4;
            int c8 = (tid & 15) * 8;
            const float* bp = &B[(size_t)(k0 + krow) * HH + c8];
            *(float4*)&Bs[krow][c8] = *(const float4*)bp;
            *(float4*)&Bs[krow][c8 + 4] = *(const float4*)(bp + 4);
        }
        __syncthreads();
#pragma unroll
        for (int kk = 0; kk < 16; kk++) {
            float a0 = As[kk][ty * 2];
            float a1 = As[kk][ty * 2 + 1];
            float4 b0 = *(const float4*)&Bs[kk][tx * 4];
            float4 b1 = *(const float4*)&Bs[kk][64 + tx * 4];
            float bv[8] = {b0.x, b0.y, b0.z, b0.w, b1.x, b1.y, b1.z, b1.w};
#pragma unroll
            for (int c = 0; c < 8; c++) {
                acc[0][c] = fmaf(a0, bv[c], acc[0][c]);
                acc[1][c] = fmaf(a1, bv[c], acc[1][c]);
            }
        }
        __syncthreads();
    }
    float4 g0 = *(const float4*)&gamma[tx * 4];
    float4 g1 = *(const float4*)&gamma[64 + tx * 4];
    float4 be0 = *(const float4*)&beta[tx * 4];
    float4 be1 = *(const float4*)&beta[64 + tx * 4];
    float gv[8] = {g0.x, g0.y, g0.z, g0.w, g1.x, g1.y, g1.z, g1.w};
    float bv[8] = {be0.x, be0.y, be0.z, be0.w, be1.x, be1.y, be1.z, be1.w};
    int gb_first = batch[m0];
    int gb_last = batch[m0 + 31];
    bool uniform = (gb_first == gb_last);   // block-uniform predicate
    float vsum[8] = {0.f};
#pragma unroll
    for (int r = 0; r < 2; r++) {
        int m = m0 + ty * 2 + r;
        float4 h0 = *(const float4*)&hg[(size_t)m * HH + tx * 4];
        float4 h1 = *(const float4*)&hg[(size_t)m * HH + 64 + tx * 4];
        float v[8] = {acc[r][0] + h0.x, acc[r][1] + h0.y, acc[r][2] + h0.z, acc[r][3] + h0.w,
                      acc[r][4] + h1.x, acc[r][5] + h1.y, acc[r][6] + h1.z, acc[r][7] + h1.w};
        float sum = 0.f;
#pragma unroll
        for (int c = 0; c < 8; c++) sum += v[c];
        sum += __shfl_xor(sum, 1); sum += __shfl_xor(sum, 2);
        sum += __shfl_xor(sum, 4); sum += __shfl_xor(sum, 8);
        float mu = sum * (1.f / 128.f);
        float vs = 0.f;
#pragma unroll
        for (int c = 0; c < 8; c++) { float dd = v[c] - mu; vs += dd * dd; }
        vs += __shfl_xor(vs, 1); vs += __shfl_xor(vs, 2);
        vs += __shfl_xor(vs, 4); vs += __shfl_xor(vs, 8);
        float inv = rsqrtf(vs * (1.f / 128.f) + 1e-5f);
#pragma unroll
        for (int c = 0; c < 8; c++) v[c] = (v[c] - mu) * inv * gv[c] + bv[c];
        if (uniform) {
#pragma unroll
            for (int c = 0; c < 8; c++) vsum[c] += v[c];
        } else {
            int g = batch[m];
#pragma unroll
            for (int c = 0; c < 8; c++) {
                int col = (c < 4) ? (tx * 4 + c) : (64 + tx * 4 + (c - 4));
                atomicAdd(&ge[g * HH + col], v[c]);
            }
            if (tx == 0) atomicAdd(&counts[g], 1);
        }
    }
    if (uniform) {
        if (tid < 128) gsum[tid] = 0.f;
        __syncthreads();
#pragma unroll
        for (int c = 0; c < 8; c++) {
            int col = (c < 4) ? (tx * 4 + c) : (64 + tx * 4 + (c - 4));
            atomicAdd(&gsum[col], vsum[c]);
        }
        __syncthreads();
        if (tid < 128) atomicAdd(&ge[gb_first * HH + tid], gsum[tid]);
        if (tid == 0) atomicAdd(&counts[gb_first], 32);
    }
}

// ---------------------------------------------------------------- GCN gather, float4, 4-edge unroll
__global__ __launch_bounds__(256) void gcn_gather4(const float* __restrict__ xw,
                                                   const int* __restrict__ rowptr,
                                                   const int* __restrict__ col,
                                                   const float* __restrict__ dinv,
                                                   const float* __restrict__ b,
                                                   float* __restrict__ out) {
    int tid = threadIdx.x;
    int sub = tid & 31;
    int n = blockIdx.x * 8 + (tid >> 5);
    float dn = dinv[n];
    const float4* xw4 = (const float4*)xw;
    float4 a = xw4[(size_t)n * 32 + sub];
    float ws = dn * dn;
    float4 acc;
    acc.x = a.x * ws; acc.y = a.y * ws; acc.z = a.z * ws; acc.w = a.w * ws;
    int beg = rowptr[n], end = rowptr[n + 1];
    int e = beg;
    for (; e + 4 <= end; e += 4) {
        int s0 = col[e], s1 = col[e + 1], s2 = col[e + 2], s3 = col[e + 3];
        float w0 = dinv[s0] * dn, w1 = dinv[s1] * dn;
        float w2 = dinv[s2] * dn, w3 = dinv[s3] * dn;
        float4 v0 = xw4[(size_t)s0 * 32 + sub];
        float4 v1 = xw4[(size_t)s1 * 32 + sub];
        float4 v2 = xw4[(size_t)s2 * 32 + sub];
        float4 v3 = xw4[(size_t)s3 * 32 + sub];
        acc.x = fmaf(v0.x, w0, acc.x); acc.y = fmaf(v0.y, w0, acc.y);
        acc.z = fmaf(v0.z, w0, acc.z); acc.w = fmaf(v0.w, w0, acc.w);
        acc.x = fmaf(v1.x, w1, acc.x); acc.y = fmaf(v1.y, w1, acc.y);
        acc.z = fmaf(v1.z, w1, acc.z); acc.w = fmaf(v1.w, w1, acc.w);
        acc.x = fmaf(v2.x, w2, acc.x); acc.y = fmaf(v2.y, w2, acc.y);
        acc.z = fmaf(v2.z, w2, acc.z); acc.w = fmaf(v2.w, w2, acc.w);
        acc.x = fmaf(v3.x, w3, acc.x); acc.y = fmaf(v3.y, w3, acc.y);
        acc.z = fmaf(v3.z, w3, acc.z); acc.w = fmaf(v3.w, w3, acc.w);
    }
    for (; e < end; e++) {
        int s0 = col[e];
        float w0 = dinv[s0] * dn;
        float4 v0 = xw4[(size_t)s0 * 32 + sub];
        acc.x = fmaf(v0.x, w0, acc.x); acc.y = fmaf(v0.y, w0, acc.y);
        acc.z = fmaf(v0.z, w0, acc.z); acc.w = fmaf(v0.w, w0, acc.w);
    }
    float4 b4 = ((const float4*)b)[sub];
    acc.x = fmaxf(acc.x + b4.x, 0.f);
    acc.y = fmaxf(acc.y + b4.y, 0.f);
    acc.z = fmaxf(acc.z + b4.z, 0.f);
    acc.w = fmaxf(acc.w + b4.w, 0.f);
    ((float4*)out)[(size_t)n * 32 + sub] = acc;
}

// ---------------------------------------------------------------- conv + silu, transposed outputs
__global__ __launch_bounds__(256) void conv_silu_t(const float* __restrict__ xz,
                                                   const float* __restrict__ cw,
                                                   const float* __restrict__ cb,
                                                   float* __restrict__ xst,
                                                   float* __restrict__ szt) {
    __shared__ float tile[67][65];
    int tid = threadIdx.x;
    int t0 = blockIdx.x * 64;
    int c0 = blockIdx.y * 64;
#pragma unroll
    for (int l = 0; l < 17; l++) {
        int idx = tid + l * 256;
        if (idx < 67 * 64) {
            int r = idx >> 6, c = idx & 63;
            int gt = t0 - 3 + r;
            tile[r][c] = (gt >= 0) ? xz[(size_t)gt * 512 + c0 + c] : 0.f;
        }
    }
    __syncthreads();
    int tl = tid & 63;
    int d0 = tid >> 6;
    if (c0 < 256) {
#pragma unroll
        for (int l = 0; l < 16; l++) {
            int dl = d0 + l * 4;
            int dg = c0 + dl;
            float acc = cb[dg];
#pragma unroll
            for (int k = 0; k < DC; k++)
                acc = fmaf(tile[tl + k][dl], cw[dg * DC + k], acc);
            xst[dg * NN + t0 + tl] = siluf(acc);
        }
    } else {
#pragma unroll
        for (int l = 0; l < 16; l++) {
            int dl = d0 + l * 4;
            int dg = c0 - 256 + dl;
            szt[dg * NN + t0 + tl] = siluf(tile[tl + 3][dl]);
        }
    }
}

// ---------------------------------------------------------------- Mamba scan (LDS-staged)
__global__ __launch_bounds__(256, 6) void scan_phase1(const float* __restrict__ xst,
                                                      const float* __restrict__ dblt,
                                                      const float* __restrict__ A_log,
                                                      const float* __restrict__ W_dt,
                                                      const float* __restrict__ b_dt,
                                                      float* __restrict__ chkP,
                                                      float* __restrict__ chkH) {
    __shared__ float Td[32][68];
    __shared__ float Tx[32][68];
    __shared__ float Bs[16][68];
    __shared__ float D8[8][68];
    int tid = threadIdx.x;
    int wave = tid >> 6, lane = tid & 63;
    int sg = lane & 7, dl = lane >> 3;
    int dblk = blockIdx.x, chunk = blockIdx.y;
    int t0 = chunk * CHLEN;
    int dloc = wave * 8 + dl;
    int d = dblk * 32 + dloc;
    int s0 = 2 * sg;
#pragma unroll
    for (int p = 0; p < 2; p++) {
        int linear = tid + p * 256;
        int row = linear >> 4, c4 = (linear & 15) * 4;
        *(float4*)&Tx[row][c4] = *(const float4*)&xst[(size_t)(dblk * 32 + row) * NN + t0 + c4];
    }
    if (tid < 128) {
        int r = tid >> 4, c4 = (tid & 15) * 4;
        *(float4*)&D8[r][c4] = *(const float4*)&dblt[(size_t)r * NN + t0 + c4];
    }
    {
        int s = tid >> 4, c4 = (tid & 15) * 4;
        *(float4*)&Bs[s][c4] = *(const float4*)&dblt[(size_t)(8 + s) * NN + t0 + c4];
    }
    float A0 = -expf(A_log[d * DS + s0]);
    float A1 = -expf(A_log[d * DS + s0 + 1]);
    __syncthreads();
    {   // dt tile: 32 d x 64 t
        int row = tid >> 3;
        int tb = (tid & 7) * 8;
        int dd = dblk * 32 + row;
        float bd = b_dt[dd];
        float wv[8];
#pragma unroll
        for (int j = 0; j < 8; j++) wv[j] = W_dt[j * DI + dd];
#pragma unroll
        for (int j = 0; j < 8; j++) {
            int t = tb + j;
            float acc = bd;
#pragma unroll
            for (int k = 0; k < 8; k++) acc = fmaf(D8[k][t], wv[k], acc);
            Td[row][t] = softplusf(acc);
        }
    }
    __syncthreads();
    float h0 = 0.f, h1 = 0.f, P0 = 1.f, P1 = 1.f;
    for (int i = 0; i < CHLEN; i += 4) {
        float4 d4 = *(const float4*)&Td[dloc][i];
        float4 x4 = *(const float4*)&Tx[dloc][i];
        float4 b04 = *(const float4*)&Bs[s0][i];
        float4 b14 = *(const float4*)&Bs[s0 + 1][i];
#define P1S(U) { float dtv = d4.U; float a0 = __expf(dtv * A0); float a1 = __expf(dtv * A1); \
        float dx = dtv * x4.U; h0 = fmaf(a0, h0, dx * b04.U); h1 = fmaf(a1, h1, dx * b14.U); \
        P0 *= a0; P1 *= a1; }
        P1S(x) P1S(y) P1S(z) P1S(w)
#undef P1S
    }
    int idx = chunk * 4096 + d * DS + s0;
    float2 vP; vP.x = P0; vP.y = P1;
    float2 vH; vH.x = h0; vH.y = h1;
    *(float2*)(chkP + idx) = vP;
    *(float2*)(chkH + idx) = vH;
}

// single phase2: serial over all chunks with 8-deep batched prefetch
__global__ void scan_phase2(const float* __restrict__ chkP, const float* __restrict__ chkH,
                            float* __restrict__ init) {
    int idx = blockIdx.x * blockDim.x + threadIdx.x;  // 4096 total
    float h = 0.f;
    for (int c0 = 0; c0 < NCH; c0 += 8) {
        float p[8], q[8];
#pragma unroll
        for (int j = 0; j < 8; j++) {
            p[j] = chkP[(c0 + j) * 4096 + idx];
            q[j] = chkH[(c0 + j) * 4096 + idx];
        }
#pragma unroll
        for (int j = 0; j < 8; j++) {
            init[(c0 + j) * 4096 + idx] = h;
            h = fmaf(p[j], h, q[j]);
        }
    }
}

// phase3: D8 overlaid into Cs buffer; sz prefetched into registers before the scan loop
__global__ __launch_bounds__(256, 6) void scan_phase3(const float* __restrict__ xst,
                                                      const float* __restrict__ dblt,
                                                      const float* __restrict__ A_log,
                                                      const float* __restrict__ W_dt,
                                                      const float* __restrict__ b_dt,
                                                      const float* __restrict__ init,
                                                      const float* __restrict__ D_p,
                                                      const float* __restrict__ szt,
                                                      float* __restrict__ yt) {
    __shared__ float Td[32][68];
    __shared__ float Tx[32][68];
    __shared__ float Bs[16][68];
    __shared__ float CsD8[16][68];
    int tid = threadIdx.x;
    int wave = tid >> 6, lane = tid & 63;
    int sg = lane & 7, dl = lane >> 3;
    int dblk = blockIdx.x, chunk = blockIdx.y;
    int t0 = chunk * CHLEN;
    int dloc = wave * 8 + dl;
    int d = dblk * 32 + dloc;
    int s0 = 2 * sg;
#pragma unroll
    for (int p = 0; p < 2; p++) {
        int linear = tid + p * 256;
        int row = linear >> 4, c4 = (linear & 15) * 4;
        *(float4*)&Tx[row][c4] = *(const float4*)&xst[(size_t)(dblk * 32 + row) * NN + t0 + c4];
    }
    if (tid < 128) {
        int r = tid >> 4, c4 = (tid & 15) * 4;
        *(float4*)&CsD8[r][c4] = *(const float4*)&dblt[(size_t)r * NN + t0 + c4];  // D8
    }
    {
        int s = tid >> 4, c4 = (tid & 15) * 4;
        *(float4*)&Bs[s][c4] = *(const float4*)&dblt[(size_t)(8 + s) * NN + t0 + c4];
    }
    float A0 = -expf(A_log[d * DS + s0]);
    float A1 = -expf(A_log[d * DS + s0 + 1]);
    float Dd = D_p[d];
    float2 ini = *(const float2*)(init + chunk * 4096 + d * DS + s0);
    float h0 = ini.x, h1 = ini.y;
    __syncthreads();
    {   // dt tile from D8 (CsD8 rows 0..7)
        int row = tid >> 3;
        int tb = (tid & 7) * 8;
        int dd = dblk * 32 + row;
        float bd = b_dt[dd];
        float wv[8];
#pragma unroll
        for (int j = 0; j < 8; j++) wv[j] = W_dt[j * DI + dd];
#pragma unroll
        for (int j = 0; j < 8; j++) {
            int t = tb + j;
            float acc = bd;
#pragma unroll
            for (int k = 0; k < 8; k++) acc = fmaf(CsD8[k][t], wv[k], acc);
            Td[row][t] = softplusf(acc);
        }
    }
    __syncthreads();
    {   // now load C rows over the dead D8
        int s = tid >> 4, c4 = (tid & 15) * 4;
        *(float4*)&CsD8[s][c4] = *(const float4*)&dblt[(size_t)(24 + s) * NN + t0 + c4];
    }
    float szv[8];
#pragma unroll
    for (int r = 0; r < 8; r++)
        szv[r] = szt[(size_t)(dblk * 32 + wave * 8 + r) * NN + t0 + lane];
    __syncthreads();
    for (int i = 0; i < CHLEN; i += 4) {
        float4 d4 = *(const float4*)&Td[dloc][i];
        float4 x4 = *(const float4*)&Tx[dloc][i];
        float4 b04 = *(const float4*)&Bs[s0][i];
        float4 b14 = *(const float4*)&Bs[s0 + 1][i];
        float4 c04 = *(const float4*)&CsD8[s0][i];
        float4 c14 = *(const float4*)&CsD8[s0 + 1][i];
        float4 yv;
#define P3S(U) { float dtv = d4.U; float a0 = __expf(dtv * A0); float a1 = __expf(dtv * A1); \
        float dx = dtv * x4.U; h0 = fmaf(a0, h0, dx * b04.U); h1 = fmaf(a1, h1, dx * b14.U); \
        float c = fmaf(h1, c14.U, h0 * c04.U); \
        c += __shfl_xor(c, 1); c += __shfl_xor(c, 2); c += __shfl_xor(c, 4); \
        yv.U = c + Dd * x4.U; }
        P3S(x) P3S(y) P3S(z) P3S(w)
#undef P3S
        if (sg == 0) *(float4*)&Td[dloc][i] = yv;  // in-place: this wave's row only
    }
#pragma unroll
    for (int r = 0; r < 8; r++) {
        int row = wave * 8 + r;
        yt[(size_t)(dblk * 32 + row) * NN + t0 + lane] = Td[row][lane] * szv[r];
    }
}

// ---------------------------------------------------------------- output heads (ge_norm folded in)
__global__ void heads_kernel(const float* __restrict__ ge, const int* __restrict__ counts,
                             const float* Wc, const float* bc, const float* Wh, const float* bh,
                             const float* Wt, const float* bt, const float* Wp1, const float* bp1,
                             const float* Wp2, const float* bp2, const float* Wd, const float* bd,
                             const float* Ws, const float* bs, float* __restrict__ out) {
    int col = blockIdx.x * blockDim.x + threadIdx.x;
    int b = blockIdx.y;
    if (col >= OUTW) return;
    const float* W; const float* bi; int lc, w;
    if (col < 1)         { W = Wc;  bi = bc;  lc = col;        w = 1; }
    else if (col < 5)    { W = Wh;  bi = bh;  lc = col - 1;    w = 4; }
    else if (col < 8)    { W = Wt;  bi = bt;  lc = col - 5;    w = 3; }
    else if (col < 520)  { W = Wp1; bi = bp1; lc = col - 8;    w = 512; }
    else if (col < 1032) { W = Wp2; bi = bp2; lc = col - 520;  w = 512; }
    else if (col < 1544) { W = Wd;  bi = bd;  lc = col - 1032; w = 512; }
    else                 { W = Ws;  bi = bs;  lc = col - 1544; w = 8; }
    float scale = 1.f / fmaxf((float)counts[b], 1.f);
    float dot = 0.f;
#pragma unroll 8
    for (int f = 0; f < HH; f++) dot = fmaf(ge[b * HH + f], W[f * w + lc], dot);
    out[(size_t)b * OUTW + col] = bi[lc] + scale * dot;
}

// ---------------------------------------------------------------- launch
extern "C" void kernel_launch(void* const* d_in, const int* in_sizes, int n_in,
                              void* d_out, int out_size, void* d_ws, size_t ws_size,
                              hipStream_t stream) {
    const float* nf      = (const float*)d_in[0];
    const int*   ei      = (const int*)d_in[1];
    const int*   batch   = (const int*)d_in[2];
    const float* W_in    = (const float*)d_in[3];
    const float* b_in    = (const float*)d_in[4];
    const float* W_g1    = (const float*)d_in[5];
    const float* b_g1    = (const float*)d_in[6];
    const float* W_g2    = (const float*)d_in[7];
    const float* b_g2    = (const float*)d_in[8];
    const float* W_inproj= (const float*)d_in[9];
    const float* conv_w  = (const float*)d_in[10];
    const float* conv_b  = (const float*)d_in[11];
    const float* W_xproj = (const float*)d_in[12];
    const float* W_dt    = (const float*)d_in[13];
    const float* b_dt    = (const float*)d_in[14];
    const float* A_log   = (const float*)d_in[15];
    const float* D_p     = (const float*)d_in[16];
    const float* W_out   = (const float*)d_in[17];
    const float* gamma   = (const float*)d_in[18];
    const float* beta    = (const float*)d_in[19];
    const float* Wc = (const float*)d_in[20]; const float* bc = (const float*)d_in[21];
    const float* Wh = (const float*)d_in[22]; const float* bh = (const float*)d_in[23];
    const float* Wt = (const float*)d_in[24]; const float* bt = (const float*)d_in[25];
    const float* Wp1= (const float*)d_in[26]; const float* bp1= (const float*)d_in[27];
    const float* Wp2= (const float*)d_in[28]; const float* bp2= (const float*)d_in[29];
    const float* Wd = (const float*)d_in[30]; const float* bd = (const float*)d_in[31];
    const float* Ws = (const float*)d_in[32]; const float* bs = (const float*)d_in[33];

    const int* e_src = ei;
    const int* e_dst = ei + EE;

    // workspace layout (floats, then ints)
    float* w = (float*)d_ws;
    size_t o = 0;
    float* F0   = w + o; o += (size_t)NN * HH;   // dead during scan -> CHP/CHH
    float* F1   = w + o; o += (size_t)NN * HH;   // dead during scan -> INI
    float* F2   = w + o; o += (size_t)NN * HH;
    float* XZ   = w + o; o += (size_t)NN * 512;  // dead after conv_silu_t; reused:
    float* YT   = XZ;                             //   y^T [DI][NN]
    float* XST  = w + o; o += (size_t)NN * DI;   // x (conv+silu), transposed [DI][NN]
    float* SZT  = w + o; o += (size_t)NN * DI;   // silu(z), transposed [DI][NN]
    float* DBLT = w + o; o += (size_t)NN * 40;   // [40][NN]; 0..7 = dt-proj^T, 8..23 = B^T, 24..39 = C^T
    float* GE   = w + o; o += BB * HH;
    float* DINV = w + o; o += NN;
    int* ip = (int*)(w + o);
    int* CNT    = ip; ip += NN;
    int* ROWPTR = ip; ip += NN + 1;
    int* CURSOR = ip; ip += NN;
    int* COL    = ip; ip += EE;
    int* COUNTS = ip; ip += BB;

    // overlays (regions dead during the scan)
    float* CHP  = F0;                         // NCH*4096 = 1M floats
    float* CHH  = F0 + (size_t)NCH * 4096;    // 1M floats (F0 holds 2M)
    float* INI  = F1;                         // NCH*4096 = 1M floats (F1 holds 2M)

    // zero scratch (single kernel instead of 3 memsets)
    zero_kernel<<<(NN + 255) / 256, 256, 0, stream>>>(CNT, GE, COUNTS);

    // CSR build
    deg_kernel<<<EE / 256, 256, 0, stream>>>(e_dst, CNT);
    prefix_kernel<<<1, 1024, 0, stream>>>(CNT, ROWPTR, CURSOR, DINV);
    scatter_kernel<<<EE / 256, 256, 0, stream>>>(e_src, e_dst, CURSOR, COL);

    // h0 = relu(nf @ W_in + b_in)
    gemm_k<<<dim3(2, NN / 64), 256, 0, stream>>>(nf, W_in, b_in, F0, NN, HH, FF, 1);
    // GCN layer 1
    gemm_k<<<dim3(2, NN / 64), 256, 0, stream>>>(F0, W_g1, nullptr, F1, NN, HH, HH, 0);
    gcn_gather4<<<NN / 8, 256, 0, stream>>>(F1, ROWPTR, COL, DINV, b_g1, F0);
    // GCN layer 2
    gemm_k<<<dim3(2, NN / 64), 256, 0, stream>>>(F0, W_g2, nullptr, F1, NN, HH, HH, 0);
    gcn_gather4<<<NN / 8, 256, 0, stream>>>(F1, ROWPTR, COL, DINV, b_g2, F2);  // F2 = h_gnn

    // xz = h_gnn @ W_inproj (512-thread big-tile GEMM)
    gemm_big512<<<dim3(4, NN / 128), 512, 0, stream>>>(F2, W_inproj, XZ, NN, 512, HH);
    // conv + silu -> XST; silu(z) -> SZT (both transposed)
    conv_silu_t<<<dim3(NN / 64, 8), 256, 0, stream>>>(XZ, conv_w, conv_b, XST, SZT);
    // dbl = xs @ W_xproj, written directly transposed -> DBLT (fused)
    gemm_at_dblt<<<NN / 64, 256, 0, stream>>>(XST, W_xproj, DBLT);

    // Mamba scan (dt fused into phase1/phase3; single phase2)
    scan_phase1<<<dim3(8, NCH), 256, 0, stream>>>(XST, DBLT, A_log, W_dt, b_dt, CHP, CHH);
    scan_phase2<<<16, 256, 0, stream>>>(CHP, CHH, INI);
    scan_phase3<<<dim3(8, NCH), 256, 0, stream>>>(XST, DBLT, A_log, W_dt, b_dt, INI, D_p, SZT, YT);

    // h_mamba = y @ W_out; + h_gnn; LayerNorm; pooled directly into GE (fused)
    gemm_at_ln_pool<<<NN / 32, 256, 0, stream>>>(YT, W_out, F2, gamma, beta, batch, GE, COUNTS);

    // heads (ge_norm folded in)
    heads_kernel<<<dim3((OUTW + 127) / 128, BB), 128, 0, stream>>>(
        GE, COUNTS, Wc, bc, Wh, bh, Wt, bt, Wp1, bp1, Wp2, bp2, Wd, bd, Ws, bs, (float*)d_out);
}

// Round 14
// 405.631 us; speedup vs baseline: 1.0081x; 1.0081x over previous
//
#include <hip/hip_runtime.h>
#include <math.h>

#define NN 16384
#define EE 262144
#define FF 32
#define HH 128
#define BB 16
#define DI 256
#define DS 16
#define DC 4
#define DTR 8
#define OUTW 1552
#define NCH 256
#define CHLEN 64    // NCH*CHLEN == NN

// ---------------------------------------------------------------- utilities
__device__ __forceinline__ float siluf(float v) { return v / (1.f + __expf(-v)); }
__device__ __forceinline__ float softplusf(float v) {
    return fmaxf(v, 0.f) + __logf(1.f + __expf(-fabsf(v)));
}

// ---------------------------------------------------------------- zero scratch (replaces 3 memsets)
__global__ void zero_kernel(int* __restrict__ cnt, float* __restrict__ ge,
                            int* __restrict__ counts) {
    int idx = blockIdx.x * blockDim.x + threadIdx.x;
    if (idx < NN) cnt[idx] = 0;
    if (idx < BB * HH) ge[idx] = 0.f;
    if (idx < BB) counts[idx] = 0;
}

// ---------------------------------------------------------------- CSR build
__global__ void deg_kernel(const int* __restrict__ dst, int* __restrict__ cnt) {
    int e = blockIdx.x * blockDim.x + threadIdx.x;
    if (e < EE) atomicAdd(&cnt[dst[e]], 1);
}

__global__ __launch_bounds__(1024) void prefix_kernel(const int* __restrict__ cnt,
                                                      int* __restrict__ rowptr,
                                                      int* __restrict__ cursor,
                                                      float* __restrict__ dinv) {
    __shared__ int part[1024];
    int tid = threadIdx.x;
    int4 c4[4];
#pragma unroll
    for (int j = 0; j < 4; j++) c4[j] = ((const int4*)cnt)[tid * 4 + j];
    int v[16] = {c4[0].x, c4[0].y, c4[0].z, c4[0].w, c4[1].x, c4[1].y, c4[1].z, c4[1].w,
                 c4[2].x, c4[2].y, c4[2].z, c4[2].w, c4[3].x, c4[3].y, c4[3].z, c4[3].w};
    int s = 0;
#pragma unroll
    for (int j = 0; j < 16; j++) s += v[j];
    part[tid] = s;
    __syncthreads();
    for (int off = 1; off < 1024; off <<= 1) {
        int t = (tid >= off) ? part[tid - off] : 0;
        __syncthreads();
        part[tid] += t;
        __syncthreads();
    }
    int running = part[tid] - s;
    int rp[16];
    float dv[16];
#pragma unroll
    for (int j = 0; j < 16; j++) {
        rp[j] = running;
        running += v[j];
        dv[j] = rsqrtf((float)(v[j] + 1));  // +1 self loop
    }
#pragma unroll
    for (int j = 0; j < 4; j++) {
        int4 r4; r4.x = rp[j*4]; r4.y = rp[j*4+1]; r4.z = rp[j*4+2]; r4.w = rp[j*4+3];
        ((int4*)rowptr)[tid * 4 + j] = r4;
        ((int4*)cursor)[tid * 4 + j] = r4;
        float4 d4; d4.x = dv[j*4]; d4.y = dv[j*4+1]; d4.z = dv[j*4+2]; d4.w = dv[j*4+3];
        ((float4*)dinv)[tid * 4 + j] = d4;
    }
    if (tid == 1023) rowptr[NN] = part[1023];
}

__global__ void scatter_kernel(const int* __restrict__ src, const int* __restrict__ dst,
                               int* __restrict__ cursor, int* __restrict__ col) {
    int e = blockIdx.x * blockDim.x + threadIdx.x;
    if (e < EE) {
        int d = dst[e];
        int pos = atomicAdd(&cursor[d], 1);
        col[pos] = src[e];
    }
}

// ---------------------------------------------------------------- GEMM (fp32, 64x64 tile)
__global__ __launch_bounds__(256) void gemm_k(const float* __restrict__ A,
                                              const float* __restrict__ B,
                                              const float* __restrict__ bias,
                                              float* __restrict__ C,
                                              int M, int Nn, int K, int act) {
    __shared__ float As[16][68];
    __shared__ float Bs[16][68];
    int tid = threadIdx.x;
    int m0 = blockIdx.y * 64;
    int n0 = blockIdx.x * 64;
    int ty = tid >> 4, tx = tid & 15;
    float acc[4][4] = {{0.f}};
    for (int k0 = 0; k0 < K; k0 += 16) {
#pragma unroll
        for (int l = 0; l < 4; l++) {
            int idx = tid + l * 256;
            int i = idx >> 4, j = idx & 15;
            As[j][i] = A[(size_t)(m0 + i) * K + k0 + j];
        }
#pragma unroll
        for (int l = 0; l < 4; l++) {
            int idx = tid + l * 256;
            int i = idx >> 6, j = idx & 63;
            int n = n0 + j;
            Bs[i][j] = (n < Nn) ? B[(size_t)(k0 + i) * Nn + n] : 0.f;
        }
        __syncthreads();
#pragma unroll
        for (int kk = 0; kk < 16; kk++) {
            float4 a4 = *(const float4*)&As[kk][ty * 4];
            float4 b4 = *(const float4*)&Bs[kk][tx * 4];
            float av[4] = {a4.x, a4.y, a4.z, a4.w};
            float bv[4] = {b4.x, b4.y, b4.z, b4.w};
#pragma unroll
            for (int r = 0; r < 4; r++)
#pragma unroll
                for (int c = 0; c < 4; c++) acc[r][c] = fmaf(av[r], bv[c], acc[r][c]);
        }
        __syncthreads();
    }
    int nb = n0 + tx * 4;
    if (nb < Nn) {
        float4 bi4 = {0.f, 0.f, 0.f, 0.f};
        if (bias) bi4 = *(const float4*)&bias[nb];
#pragma unroll
        for (int r = 0; r < 4; r++) {
            int m = m0 + ty * 4 + r;
            float4 v;
            v.x = acc[r][0] + bi4.x; v.y = acc[r][1] + bi4.y;
            v.z = acc[r][2] + bi4.z; v.w = acc[r][3] + bi4.w;
            if (act == 1) {
                v.x = fmaxf(v.x, 0.f); v.y = fmaxf(v.y, 0.f);
                v.z = fmaxf(v.z, 0.f); v.w = fmaxf(v.w, 0.f);
            }
            *(float4*)&C[(size_t)m * Nn + nb] = v;
        }
    }
}

// ---------------------------------------------------------------- big-tile GEMM, 512 threads
__global__ __launch_bounds__(512, 4) void gemm_big512(const float* __restrict__ A,
                                                      const float* __restrict__ B,
                                                      float* __restrict__ C,
                                                      int M, int Nn, int K) {
    __shared__ float As[16][132];
    __shared__ float Bs[16][132];
    int tid = threadIdx.x;
    int m0 = blockIdx.y * 128;
    int n0 = blockIdx.x * 128;
    int ty = tid >> 4;
    int tx = tid & 15;
    float acc[4][8] = {{0.f}};
    for (int k0 = 0; k0 < K; k0 += 16) {
        {
            int m = tid >> 2;
            int kc = (tid & 3) * 4;
            float4 a = *(const float4*)&A[(size_t)(m0 + m) * K + k0 + kc];
            As[kc + 0][m] = a.x; As[kc + 1][m] = a.y;
            As[kc + 2][m] = a.z; As[kc + 3][m] = a.w;
        }
        {
            int krow = tid >> 5;
            int c4 = (tid & 31) * 4;
            *(float4*)&Bs[krow][c4] = *(const float4*)&B[(size_t)(k0 + krow) * Nn + n0 + c4];
        }
        __syncthreads();
#pragma unroll
        for (int kk = 0; kk < 16; kk++) {
            float4 a4 = *(const float4*)&As[kk][ty * 4];
            float4 b0 = *(const float4*)&Bs[kk][tx * 4];
            float4 b1 = *(const float4*)&Bs[kk][64 + tx * 4];
            float av[4] = {a4.x, a4.y, a4.z, a4.w};
            float bv[8] = {b0.x, b0.y, b0.z, b0.w, b1.x, b1.y, b1.z, b1.w};
#pragma unroll
            for (int r = 0; r < 4; r++)
#pragma unroll
                for (int c = 0; c < 8; c++) acc[r][c] = fmaf(av[r], bv[c], acc[r][c]);
        }
        __syncthreads();
    }
#pragma unroll
    for (int r = 0; r < 4; r++) {
        int m = m0 + ty * 4 + r;
        float4 v0, v1;
        v0.x = acc[r][0]; v0.y = acc[r][1]; v0.z = acc[r][2]; v0.w = acc[r][3];
        v1.x = acc[r][4]; v1.y = acc[r][5]; v1.z = acc[r][6]; v1.w = acc[r][7];
        *(float4*)&C[(size_t)m * Nn + n0 + tx * 4] = v0;
        *(float4*)&C[(size_t)m * Nn + n0 + 64 + tx * 4] = v1;
    }
}

// ---------------------------------------------------------------- xproj GEMM (A^T) + transposed output
__global__ __launch_bounds__(256) void gemm_at_dblt(const float* __restrict__ AT,
                                                    const float* __restrict__ B,
                                                    float* __restrict__ dblt) {
    __shared__ float As[16][68];
    __shared__ float Bs[16][68];
    __shared__ float Ct[64][41];
    int tid = threadIdx.x;
    int m0 = blockIdx.x * 64;
    int ty = tid >> 4, tx = tid & 15;
    float acc[4][4] = {{0.f}};
    for (int k0 = 0; k0 < DI; k0 += 16) {
#pragma unroll
        for (int l = 0; l < 4; l++) {
            int idx = tid + l * 256;
            int kk = idx >> 6, i = idx & 63;
            As[kk][i] = AT[(size_t)(k0 + kk) * NN + m0 + i];
        }
#pragma unroll
        for (int l = 0; l < 4; l++) {
            int idx = tid + l * 256;
            int i = idx >> 6, j = idx & 63;
            Bs[i][j] = (j < 40) ? B[(size_t)(k0 + i) * 40 + j] : 0.f;
        }
        __syncthreads();
#pragma unroll
        for (int kk = 0; kk < 16; kk++) {
            float4 a4 = *(const float4*)&As[kk][ty * 4];
            float4 b4 = *(const float4*)&Bs[kk][tx * 4];
            float av[4] = {a4.x, a4.y, a4.z, a4.w};
            float bv[4] = {b4.x, b4.y, b4.z, b4.w};
#pragma unroll
            for (int r = 0; r < 4; r++)
#pragma unroll
                for (int c = 0; c < 4; c++) acc[r][c] = fmaf(av[r], bv[c], acc[r][c]);
        }
        __syncthreads();
    }
    if (tx * 4 < 40) {
#pragma unroll
        for (int r = 0; r < 4; r++) {
            int m = ty * 4 + r;
            Ct[m][tx * 4 + 0] = acc[r][0];
            Ct[m][tx * 4 + 1] = acc[r][1];
            Ct[m][tx * 4 + 2] = acc[r][2];
            Ct[m][tx * 4 + 3] = acc[r][3];
        }
    }
    __syncthreads();
#pragma unroll
    for (int l = 0; l < 10; l++) {
        int idx = tid + l * 256;
        int n = idx >> 6, m = idx & 63;
        dblt[(size_t)n * NN + m0 + m] = Ct[m][n];
    }
}

// ---------------------------------------------------------------- fused W_out GEMM + add + LayerNorm
__global__ __launch_bounds__(256) void gemm_at_ln(const float* __restrict__ AT,
                                                  const float* __restrict__ B,
                                                  const float* __restrict__ hg,
                                                  const float* __restrict__ gamma,
                                                  const float* __restrict__ beta,
                                                  float* __restrict__ out) {
    __shared__ float As[16][36];
    __shared__ float Bs[16][132];
    int tid = threadIdx.x;
    int m0 = blockIdx.x * 32;
    int ty = tid >> 4, tx = tid & 15;
    float acc[2][8] = {{0.f}};
    for (int k0 = 0; k0 < 256; k0 += 16) {
        {
            int idx = tid * 2;
            int kk = idx >> 5, i = idx & 31;
            As[kk][i] = AT[(size_t)(k0 + kk) * NN + m0 + i];
            As[kk][i + 1] = AT[(size_t)(k0 + kk) * NN + m0 + i + 1];
        }
        {
            int krow = tid >> 4;
            int c8 = (tid & 15) * 8;
            const float* bp = &B[(size_t)(k0 + krow) * HH + c8];
            *(float4*)&Bs[krow][c8] = *(const float4*)bp;
            *(float4*)&Bs[krow][c8 + 4] = *(const float4*)(bp + 4);
        }
        __syncthreads();
#pragma unroll
        for (int kk = 0; kk < 16; kk++) {
            float a0 = As[kk][ty * 2];
            float a1 = As[kk][ty * 2 + 1];
            float4 b0 = *(const float4*)&Bs[kk][tx * 4];
            float4 b1 = *(const float4*)&Bs[kk][64 + tx * 4];
            float bv[8] = {b0.x, b0.y, b0.z, b0.w, b1.x, b1.y, b1.z, b1.w};
#pragma unroll
            for (int c = 0; c < 8; c++) {
                acc[0][c] = fmaf(a0, bv[c], acc[0][c]);
                acc[1][c] = fmaf(a1, bv[c], acc[1][c]);
            }
        }
        __syncthreads();
    }
    float4 g0 = *(const float4*)&gamma[tx * 4];
    float4 g1 = *(const float4*)&gamma[64 + tx * 4];
    float4 be0 = *(const float4*)&beta[tx * 4];
    float4 be1 = *(const float4*)&beta[64 + tx * 4];
    float gv[8] = {g0.x, g0.y, g0.z, g0.w, g1.x, g1.y, g1.z, g1.w};
    float bv[8] = {be0.x, be0.y, be0.z, be0.w, be1.x, be1.y, be1.z, be1.w};
#pragma unroll
    for (int r = 0; r < 2; r++) {
        int m = m0 + ty * 2 + r;
        float4 h0 = *(const float4*)&hg[(size_t)m * HH + tx * 4];
        float4 h1 = *(const float4*)&hg[(size_t)m * HH + 64 + tx * 4];
        float v[8] = {acc[r][0] + h0.x, acc[r][1] + h0.y, acc[r][2] + h0.z, acc[r][3] + h0.w,
                      acc[r][4] + h1.x, acc[r][5] + h1.y, acc[r][6] + h1.z, acc[r][7] + h1.w};
        float sum = 0.f;
#pragma unroll
        for (int c = 0; c < 8; c++) sum += v[c];
        sum += __shfl_xor(sum, 1); sum += __shfl_xor(sum, 2);
        sum += __shfl_xor(sum, 4); sum += __shfl_xor(sum, 8);
        float mu = sum * (1.f / 128.f);
        float vs = 0.f;
#pragma unroll
        for (int c = 0; c < 8; c++) { float dd = v[c] - mu; vs += dd * dd; }
        vs += __shfl_xor(vs, 1); vs += __shfl_xor(vs, 2);
        vs += __shfl_xor(vs, 4); vs += __shfl_xor(vs, 8);
        float inv = rsqrtf(vs * (1.f / 128.f) + 1e-5f);
        float4 o0, o1;
        o0.x = (v[0] - mu) * inv * gv[0] + bv[0];
        o0.y = (v[1] - mu) * inv * gv[1] + bv[1];
        o0.z = (v[2] - mu) * inv * gv[2] + bv[2];
        o0.w = (v[3] - mu) * inv * gv[3] + bv[3];
        o1.x = (v[4] - mu) * inv * gv[4] + bv[4];
        o1.y = (v[5] - mu) * inv * gv[5] + bv[5];
        o1.z = (v[6] - mu) * inv * gv[6] + bv[6];
        o1.w = (v[7] - mu) * inv * gv[7] + bv[7];
        *(float4*)&out[(size_t)m * HH + tx * 4] = o0;
        *(float4*)&out[(size_t)m * HH + 64 + tx * 4] = o1;
    }
}

// ---------------------------------------------------------------- GCN gather, float4, 4-edge unroll
__global__ __launch_bounds__(256) void gcn_gather4(const float* __restrict__ xw,
                                                   const int* __restrict__ rowptr,
                                                   const int* __restrict__ col,
                                                   const float* __restrict__ dinv,
                                                   const float* __restrict__ b,
                                                   float* __restrict__ out) {
    int tid = threadIdx.x;
    int sub = tid & 31;
    int n = blockIdx.x * 8 + (tid >> 5);
    float dn = dinv[n];
    const float4* xw4 = (const float4*)xw;
    float4 a = xw4[(size_t)n * 32 + sub];
    float ws = dn * dn;
    float4 acc;
    acc.x = a.x * ws; acc.y = a.y * ws; acc.z = a.z * ws; acc.w = a.w * ws;
    int beg = rowptr[n], end = rowptr[n + 1];
    int e = beg;
    for (; e + 4 <= end; e += 4) {
        int s0 = col[e], s1 = col[e + 1], s2 = col[e + 2], s3 = col[e + 3];
        float w0 = dinv[s0] * dn, w1 = dinv[s1] * dn;
        float w2 = dinv[s2] * dn, w3 = dinv[s3] * dn;
        float4 v0 = xw4[(size_t)s0 * 32 + sub];
        float4 v1 = xw4[(size_t)s1 * 32 + sub];
        float4 v2 = xw4[(size_t)s2 * 32 + sub];
        float4 v3 = xw4[(size_t)s3 * 32 + sub];
        acc.x = fmaf(v0.x, w0, acc.x); acc.y = fmaf(v0.y, w0, acc.y);
        acc.z = fmaf(v0.z, w0, acc.z); acc.w = fmaf(v0.w, w0, acc.w);
        acc.x = fmaf(v1.x, w1, acc.x); acc.y = fmaf(v1.y, w1, acc.y);
        acc.z = fmaf(v1.z, w1, acc.z); acc.w = fmaf(v1.w, w1, acc.w);
        acc.x = fmaf(v2.x, w2, acc.x); acc.y = fmaf(v2.y, w2, acc.y);
        acc.z = fmaf(v2.z, w2, acc.z); acc.w = fmaf(v2.w, w2, acc.w);
        acc.x = fmaf(v3.x, w3, acc.x); acc.y = fmaf(v3.y, w3, acc.y);
        acc.z = fmaf(v3.z, w3, acc.z); acc.w = fmaf(v3.w, w3, acc.w);
    }
    for (; e < end; e++) {
        int s0 = col[e];
        float w0 = dinv[s0] * dn;
        float4 v0 = xw4[(size_t)s0 * 32 + sub];
        acc.x = fmaf(v0.x, w0, acc.x); acc.y = fmaf(v0.y, w0, acc.y);
        acc.z = fmaf(v0.z, w0, acc.z); acc.w = fmaf(v0.w, w0, acc.w);
    }
    float4 b4 = ((const float4*)b)[sub];
    acc.x = fmaxf(acc.x + b4.x, 0.f);
    acc.y = fmaxf(acc.y + b4.y, 0.f);
    acc.z = fmaxf(acc.z + b4.z, 0.f);
    acc.w = fmaxf(acc.w + b4.w, 0.f);
    ((float4*)out)[(size_t)n * 32 + sub] = acc;
}

// ---------------------------------------------------------------- conv + silu, transposed outputs
__global__ __launch_bounds__(256) void conv_silu_t(const float* __restrict__ xz,
                                                   const float* __restrict__ cw,
                                                   const float* __restrict__ cb,
                                                   float* __restrict__ xst,
                                                   float* __restrict__ szt) {
    __shared__ float tile[67][65];
    int tid = threadIdx.x;
    int t0 = blockIdx.x * 64;
    int c0 = blockIdx.y * 64;
#pragma unroll
    for (int l = 0; l < 17; l++) {
        int idx = tid + l * 256;
        if (idx < 67 * 64) {
            int r = idx >> 6, c = idx & 63;
            int gt = t0 - 3 + r;
            tile[r][c] = (gt >= 0) ? xz[(size_t)gt * 512 + c0 + c] : 0.f;
        }
    }
    __syncthreads();
    int tl = tid & 63;
    int d0 = tid >> 6;
    if (c0 < 256) {
#pragma unroll
        for (int l = 0; l < 16; l++) {
            int dl = d0 + l * 4;
            int dg = c0 + dl;
            float acc = cb[dg];
#pragma unroll
            for (int k = 0; k < DC; k++)
                acc = fmaf(tile[tl + k][dl], cw[dg * DC + k], acc);
            xst[dg * NN + t0 + tl] = siluf(acc);
        }
    } else {
#pragma unroll
        for (int l = 0; l < 16; l++) {
            int dl = d0 + l * 4;
            int dg = c0 - 256 + dl;
            szt[dg * NN + t0 + tl] = siluf(tile[tl + 3][dl]);
        }
    }
}

// ---------------------------------------------------------------- Mamba scan (LDS-staged)
__global__ __launch_bounds__(256, 6) void scan_phase1(const float* __restrict__ xst,
                                                      const float* __restrict__ dblt,
                                                      const float* __restrict__ A_log,
                                                      const float* __restrict__ W_dt,
                                                      const float* __restrict__ b_dt,
                                                      float* __restrict__ chkP,
                                                      float* __restrict__ chkH) {
    __shared__ float Td[32][68];
    __shared__ float Tx[32][68];
    __shared__ float Bs[16][68];
    __shared__ float D8[8][68];
    int tid = threadIdx.x;
    int wave = tid >> 6, lane = tid & 63;
    int sg = lane & 7, dl = lane >> 3;
    int dblk = blockIdx.x, chunk = blockIdx.y;
    int t0 = chunk * CHLEN;
    int dloc = wave * 8 + dl;
    int d = dblk * 32 + dloc;
    int s0 = 2 * sg;
#pragma unroll
    for (int p = 0; p < 2; p++) {
        int linear = tid + p * 256;
        int row = linear >> 4, c4 = (linear & 15) * 4;
        *(float4*)&Tx[row][c4] = *(const float4*)&xst[(size_t)(dblk * 32 + row) * NN + t0 + c4];
    }
    if (tid < 128) {
        int r = tid >> 4, c4 = (tid & 15) * 4;
        *(float4*)&D8[r][c4] = *(const float4*)&dblt[(size_t)r * NN + t0 + c4];
    }
    {
        int s = tid >> 4, c4 = (tid & 15) * 4;
        *(float4*)&Bs[s][c4] = *(const float4*)&dblt[(size_t)(8 + s) * NN + t0 + c4];
    }
    float A0 = -expf(A_log[d * DS + s0]);
    float A1 = -expf(A_log[d * DS + s0 + 1]);
    __syncthreads();
    {   // dt tile: 32 d x 64 t
        int row = tid >> 3;
        int tb = (tid & 7) * 8;
        int dd = dblk * 32 + row;
        float bd = b_dt[dd];
        float wv[8];
#pragma unroll
        for (int j = 0; j < 8; j++) wv[j] = W_dt[j * DI + dd];
#pragma unroll
        for (int j = 0; j < 8; j++) {
            int t = tb + j;
            float acc = bd;
#pragma unroll
            for (int k = 0; k < 8; k++) acc = fmaf(D8[k][t], wv[k], acc);
            Td[row][t] = softplusf(acc);
        }
    }
    __syncthreads();
    float h0 = 0.f, h1 = 0.f, P0 = 1.f, P1 = 1.f;
    for (int i = 0; i < CHLEN; i += 4) {
        float4 d4 = *(const float4*)&Td[dloc][i];
        float4 x4 = *(const float4*)&Tx[dloc][i];
        float4 b04 = *(const float4*)&Bs[s0][i];
        float4 b14 = *(const float4*)&Bs[s0 + 1][i];
#define P1S(U) { float dtv = d4.U; float a0 = __expf(dtv * A0); float a1 = __expf(dtv * A1); \
        float dx = dtv * x4.U; h0 = fmaf(a0, h0, dx * b04.U); h1 = fmaf(a1, h1, dx * b14.U); \
        P0 *= a0; P1 *= a1; }
        P1S(x) P1S(y) P1S(z) P1S(w)
#undef P1S
    }
    int idx = chunk * 4096 + d * DS + s0;
    float2 vP; vP.x = P0; vP.y = P1;
    float2 vH; vH.x = h0; vH.y = h1;
    *(float2*)(chkP + idx) = vP;
    *(float2*)(chkH + idx) = vH;
}

// single phase2: serial over all chunks with 8-deep batched prefetch
__global__ void scan_phase2(const float* __restrict__ chkP, const float* __restrict__ chkH,
                            float* __restrict__ init) {
    int idx = blockIdx.x * blockDim.x + threadIdx.x;  // 4096 total
    float h = 0.f;
    for (int c0 = 0; c0 < NCH; c0 += 8) {
        float p[8], q[8];
#pragma unroll
        for (int j = 0; j < 8; j++) {
            p[j] = chkP[(c0 + j) * 4096 + idx];
            q[j] = chkH[(c0 + j) * 4096 + idx];
        }
#pragma unroll
        for (int j = 0; j < 8; j++) {
            init[(c0 + j) * 4096 + idx] = h;
            h = fmaf(p[j], h, q[j]);
        }
    }
}

// phase3: D8 overlaid into Cs buffer; sz prefetched into registers before the scan loop
__global__ __launch_bounds__(256, 6) void scan_phase3(const float* __restrict__ xst,
                                                      const float* __restrict__ dblt,
                                                      const float* __restrict__ A_log,
                                                      const float* __restrict__ W_dt,
                                                      const float* __restrict__ b_dt,
                                                      const float* __restrict__ init,
                                                      const float* __restrict__ D_p,
                                                      const float* __restrict__ szt,
                                                      float* __restrict__ yt) {
    __shared__ float Td[32][68];
    __shared__ float Tx[32][68];
    __shared__ float Bs[16][68];
    __shared__ float CsD8[16][68];
    int tid = threadIdx.x;
    int wave = tid >> 6, lane = tid & 63;
    int sg = lane & 7, dl = lane >> 3;
    int dblk = blockIdx.x, chunk = blockIdx.y;
    int t0 = chunk * CHLEN;
    int dloc = wave * 8 + dl;
    int d = dblk * 32 + dloc;
    int s0 = 2 * sg;
#pragma unroll
    for (int p = 0; p < 2; p++) {
        int linear = tid + p * 256;
        int row = linear >> 4, c4 = (linear & 15) * 4;
        *(float4*)&Tx[row][c4] = *(const float4*)&xst[(size_t)(dblk * 32 + row) * NN + t0 + c4];
    }
    if (tid < 128) {
        int r = tid >> 4, c4 = (tid & 15) * 4;
        *(float4*)&CsD8[r][c4] = *(const float4*)&dblt[(size_t)r * NN + t0 + c4];  // D8
    }
    {
        int s = tid >> 4, c4 = (tid & 15) * 4;
        *(float4*)&Bs[s][c4] = *(const float4*)&dblt[(size_t)(8 + s) * NN + t0 + c4];
    }
    float A0 = -expf(A_log[d * DS + s0]);
    float A1 = -expf(A_log[d * DS + s0 + 1]);
    float Dd = D_p[d];
    float2 ini = *(const float2*)(init + chunk * 4096 + d * DS + s0);
    float h0 = ini.x, h1 = ini.y;
    __syncthreads();
    {   // dt tile from D8 (CsD8 rows 0..7)
        int row = tid >> 3;
        int tb = (tid & 7) * 8;
        int dd = dblk * 32 + row;
        float bd = b_dt[dd];
        float wv[8];
#pragma unroll
        for (int j = 0; j < 8; j++) wv[j] = W_dt[j * DI + dd];
#pragma unroll
        for (int j = 0; j < 8; j++) {
            int t = tb + j;
            float acc = bd;
#pragma unroll
            for (int k = 0; k < 8; k++) acc = fmaf(CsD8[k][t], wv[k], acc);
            Td[row][t] = softplusf(acc);
        }
    }
    __syncthreads();
    {   // now load C rows over the dead D8
        int s = tid >> 4, c4 = (tid & 15) * 4;
        *(float4*)&CsD8[s][c4] = *(const float4*)&dblt[(size_t)(24 + s) * NN + t0 + c4];
    }
    float szv[8];
#pragma unroll
    for (int r = 0; r < 8; r++)
        szv[r] = szt[(size_t)(dblk * 32 + wave * 8 + r) * NN + t0 + lane];
    __syncthreads();
    for (int i = 0; i < CHLEN; i += 4) {
        float4 d4 = *(const float4*)&Td[dloc][i];
        float4 x4 = *(const float4*)&Tx[dloc][i];
        float4 b04 = *(const float4*)&Bs[s0][i];
        float4 b14 = *(const float4*)&Bs[s0 + 1][i];
        float4 c04 = *(const float4*)&CsD8[s0][i];
        float4 c14 = *(const float4*)&CsD8[s0 + 1][i];
        float4 yv;
#define P3S(U) { float dtv = d4.U; float a0 = __expf(dtv * A0); float a1 = __expf(dtv * A1); \
        float dx = dtv * x4.U; h0 = fmaf(a0, h0, dx * b04.U); h1 = fmaf(a1, h1, dx * b14.U); \
        float c = fmaf(h1, c14.U, h0 * c04.U); \
        c += __shfl_xor(c, 1); c += __shfl_xor(c, 2); c += __shfl_xor(c, 4); \
        yv.U = c + Dd * x4.U; }
        P3S(x) P3S(y) P3S(z) P3S(w)
#undef P3S
        if (sg == 0) *(float4*)&Td[dloc][i] = yv;  // in-place: this wave's row only
    }
#pragma unroll
    for (int r = 0; r < 8; r++) {
        int row = wave * 8 + r;
        yt[(size_t)(dblk * 32 + row) * NN + t0 + lane] = Td[row][lane] * szv[r];
    }
}

// ---------------------------------------------------------------- pooling (batch sorted), 64 rows/block
__global__ void pool_kernel(const float* __restrict__ hf, const int* __restrict__ batch,
                            float* __restrict__ ge, int* __restrict__ counts) {
    int f = threadIdx.x;  // 128
    int r0 = blockIdx.x * 64;
    int gcur = batch[r0];
    float acc = 0.f;
    int cnt = 0;
    for (int i = 0; i < 64; i += 4) {
        int r = r0 + i;
        int g0 = batch[r], g3 = batch[r + 3];
        float v0 = hf[(size_t)r * HH + f];
        float v1 = hf[(size_t)(r + 1) * HH + f];
        float v2 = hf[(size_t)(r + 2) * HH + f];
        float v3 = hf[(size_t)(r + 3) * HH + f];
        if (g0 == gcur && g3 == gcur) {
            acc += (v0 + v1) + (v2 + v3);
            cnt += 4;
        } else {
            int gs[4] = {g0, batch[r + 1], batch[r + 2], g3};
            float vs[4] = {v0, v1, v2, v3};
#pragma unroll
            for (int k = 0; k < 4; k++) {
                if (gs[k] != gcur) {
                    atomicAdd(&ge[gcur * HH + f], acc);
                    if (f == 0) atomicAdd(&counts[gcur], cnt);
                    acc = 0.f; cnt = 0; gcur = gs[k];
                }
                acc += vs[k];
                cnt++;
            }
        }
    }
    atomicAdd(&ge[gcur * HH + f], acc);
    if (f == 0) atomicAdd(&counts[gcur], cnt);
}

// ---------------------------------------------------------------- output heads (ge_norm folded in)
__global__ void heads_kernel(const float* __restrict__ ge, const int* __restrict__ counts,
                             const float* Wc, const float* bc, const float* Wh, const float* bh,
                             const float* Wt, const float* bt, const float* Wp1, const float* bp1,
                             const float* Wp2, const float* bp2, const float* Wd, const float* bd,
                             const float* Ws, const float* bs, float* __restrict__ out) {
    int col = blockIdx.x * blockDim.x + threadIdx.x;
    int b = blockIdx.y;
    if (col >= OUTW) return;
    const float* W; const float* bi; int lc, w;
    if (col < 1)         { W = Wc;  bi = bc;  lc = col;        w = 1; }
    else if (col < 5)    { W = Wh;  bi = bh;  lc = col - 1;    w = 4; }
    else if (col < 8)    { W = Wt;  bi = bt;  lc = col - 5;    w = 3; }
    else if (col < 520)  { W = Wp1; bi = bp1; lc = col - 8;    w = 512; }
    else if (col < 1032) { W = Wp2; bi = bp2; lc = col - 520;  w = 512; }
    else if (col < 1544) { W = Wd;  bi = bd;  lc = col - 1032; w = 512; }
    else                 { W = Ws;  bi = bs;  lc = col - 1544; w = 8; }
    float scale = 1.f / fmaxf((float)counts[b], 1.f);
    float dot = 0.f;
#pragma unroll 8
    for (int f = 0; f < HH; f++) dot = fmaf(ge[b * HH + f], W[f * w + lc], dot);
    out[(size_t)b * OUTW + col] = bi[lc] + scale * dot;
}

// ---------------------------------------------------------------- launch
extern "C" void kernel_launch(void* const* d_in, const int* in_sizes, int n_in,
                              void* d_out, int out_size, void* d_ws, size_t ws_size,
                              hipStream_t stream) {
    const float* nf      = (const float*)d_in[0];
    const int*   ei      = (const int*)d_in[1];
    const int*   batch   = (const int*)d_in[2];
    const float* W_in    = (const float*)d_in[3];
    const float* b_in    = (const float*)d_in[4];
    const float* W_g1    = (const float*)d_in[5];
    const float* b_g1    = (const float*)d_in[6];
    const float* W_g2    = (const float*)d_in[7];
    const float* b_g2    = (const float*)d_in[8];
    const float* W_inproj= (const float*)d_in[9];
    const float* conv_w  = (const float*)d_in[10];
    const float* conv_b  = (const float*)d_in[11];
    const float* W_xproj = (const float*)d_in[12];
    const float* W_dt    = (const float*)d_in[13];
    const float* b_dt    = (const float*)d_in[14];
    const float* A_log   = (const float*)d_in[15];
    const float* D_p     = (const float*)d_in[16];
    const float* W_out   = (const float*)d_in[17];
    const float* gamma   = (const float*)d_in[18];
    const float* beta    = (const float*)d_in[19];
    const float* Wc = (const float*)d_in[20]; const float* bc = (const float*)d_in[21];
    const float* Wh = (const float*)d_in[22]; const float* bh = (const float*)d_in[23];
    const float* Wt = (const float*)d_in[24]; const float* bt = (const float*)d_in[25];
    const float* Wp1= (const float*)d_in[26]; const float* bp1= (const float*)d_in[27];
    const float* Wp2= (const float*)d_in[28]; const float* bp2= (const float*)d_in[29];
    const float* Wd = (const float*)d_in[30]; const float* bd = (const float*)d_in[31];
    const float* Ws = (const float*)d_in[32]; const float* bs = (const float*)d_in[33];

    const int* e_src = ei;
    const int* e_dst = ei + EE;

    // workspace layout (floats, then ints)
    float* w = (float*)d_ws;
    size_t o = 0;
    float* F0   = w + o; o += (size_t)NN * HH;   // dead during scan -> CHP/CHH
    float* F1   = w + o; o += (size_t)NN * HH;   // dead during scan -> INI
    float* F2   = w + o; o += (size_t)NN * HH;
    float* XZ   = w + o; o += (size_t)NN * 512;  // dead after conv_silu_t; reused:
    float* YT   = XZ;                             //   y^T [DI][NN]
    float* XST  = w + o; o += (size_t)NN * DI;   // x (conv+silu), transposed [DI][NN]
    float* SZT  = w + o; o += (size_t)NN * DI;   // silu(z), transposed [DI][NN]
    float* DBLT = w + o; o += (size_t)NN * 40;   // [40][NN]; 0..7 = dt-proj^T, 8..23 = B^T, 24..39 = C^T
    float* GE   = w + o; o += BB * HH;
    float* DINV = w + o; o += NN;
    int* ip = (int*)(w + o);
    int* CNT    = ip; ip += NN;
    int* ROWPTR = ip; ip += NN + 1;
    int* CURSOR = ip; ip += NN;
    int* COL    = ip; ip += EE;
    int* COUNTS = ip; ip += BB;

    // overlays (regions dead during the scan)
    float* CHP  = F0;                         // NCH*4096 = 1M floats
    float* CHH  = F0 + (size_t)NCH * 4096;    // 1M floats (F0 holds 2M)
    float* INI  = F1;                         // NCH*4096 = 1M floats (F1 holds 2M)

    // zero scratch (single kernel instead of 3 memsets)
    zero_kernel<<<(NN + 255) / 256, 256, 0, stream>>>(CNT, GE, COUNTS);

    // CSR build
    deg_kernel<<<EE / 256, 256, 0, stream>>>(e_dst, CNT);
    prefix_kernel<<<1, 1024, 0, stream>>>(CNT, ROWPTR, CURSOR, DINV);
    scatter_kernel<<<EE / 256, 256, 0, stream>>>(e_src, e_dst, CURSOR, COL);

    // h0 = relu(nf @ W_in + b_in)
    gemm_k<<<dim3(2, NN / 64), 256, 0, stream>>>(nf, W_in, b_in, F0, NN, HH, FF, 1);
    // GCN layer 1
    gemm_k<<<dim3(2, NN / 64), 256, 0, stream>>>(F0, W_g1, nullptr, F1, NN, HH, HH, 0);
    gcn_gather4<<<NN / 8, 256, 0, stream>>>(F1, ROWPTR, COL, DINV, b_g1, F0);
    // GCN layer 2
    gemm_k<<<dim3(2, NN / 64), 256, 0, stream>>>(F0, W_g2, nullptr, F1, NN, HH, HH, 0);
    gcn_gather4<<<NN / 8, 256, 0, stream>>>(F1, ROWPTR, COL, DINV, b_g2, F2);  // F2 = h_gnn

    // xz = h_gnn @ W_inproj (512-thread big-tile GEMM)
    gemm_big512<<<dim3(4, NN / 128), 512, 0, stream>>>(F2, W_inproj, XZ, NN, 512, HH);
    // conv + silu -> XST; silu(z) -> SZT (both transposed)
    conv_silu_t<<<dim3(NN / 64, 8), 256, 0, stream>>>(XZ, conv_w, conv_b, XST, SZT);
    // dbl = xs @ W_xproj, written directly transposed -> DBLT (fused)
    gemm_at_dblt<<<NN / 64, 256, 0, stream>>>(XST, W_xproj, DBLT);

    // Mamba scan (dt fused into phase1/phase3; single phase2)
    scan_phase1<<<dim3(8, NCH), 256, 0, stream>>>(XST, DBLT, A_log, W_dt, b_dt, CHP, CHH);
    scan_phase2<<<16, 256, 0, stream>>>(CHP, CHH, INI);
    scan_phase3<<<dim3(8, NCH), 256, 0, stream>>>(XST, DBLT, A_log, W_dt, b_dt, INI, D_p, SZT, YT);

    // h_mamba = y @ W_out; + h_gnn; LayerNorm -> F0 (fused, 32-row tiles)
    gemm_at_ln<<<NN / 32, 256, 0, stream>>>(YT, W_out, F2, gamma, beta, F0);

    // pooling
    pool_kernel<<<NN / 64, HH, 0, stream>>>(F0, batch, GE, COUNTS);

    // heads (ge_norm folded in)
    heads_kernel<<<dim3((OUTW + 127) / 128, BB), 128, 0, stream>>>(
        GE, COUNTS, Wc, bc, Wh, bh, Wt, bt, Wp1, bp1, Wp2, bp2, Wd, bd, Ws, bs, (float*)d_out);
}